// Round 14
// baseline (147.969 us; speedup 1.0000x reference)
//
#include <hip/hip_runtime.h>
#include <hip/hip_bf16.h>

#define BDIM 16384
#define CDIM 128
#define FDIM 5000
#define EDIM 20000
#define ELLW 16
#define MAXOVF 20000
#define NT4  10       // n-tile QUADS: 40 n-tiles / 4

typedef __attribute__((ext_vector_type(8))) short short8;
typedef __attribute__((ext_vector_type(4))) float f32x4;
typedef __attribute__((ext_vector_type(2))) float f32x2;
typedef __attribute__((ext_vector_type(2))) int i32x2;
typedef __attribute__((ext_vector_type(8))) unsigned short upk8;
typedef __attribute__((ext_vector_type(4))) unsigned short upk4;
typedef __attribute__((ext_vector_type(2))) unsigned short upk2;
typedef __attribute__((ext_vector_type(2))) unsigned int u32x2;
typedef __attribute__((ext_vector_type(4))) unsigned int u32x4;

__device__ __forceinline__ unsigned short f2bf(float f) {
    unsigned int u = __builtin_bit_cast(unsigned int, f);
    u = (u + 0x7fffu + ((u >> 16) & 1u)) >> 16;   // RNE
    return (unsigned short)u;
}
// packed max of two u16 pairs (v_pk_max_u16)
__device__ __forceinline__ unsigned int pkmax2(unsigned int a, unsigned int b) {
#if __has_builtin(__builtin_elementwise_max)
    upk2 r = __builtin_elementwise_max(__builtin_bit_cast(upk2, a),
                                       __builtin_bit_cast(upk2, b));
    return __builtin_bit_cast(unsigned int, r);
#else
    unsigned int lo = ((a & 0xFFFFu) > (b & 0xFFFFu)) ? (a & 0xFFFFu) : (b & 0xFFFFu);
    unsigned int hi = ((a >> 16) > (b >> 16)) ? (a & 0xFFFF0000u) : (b & 0xFFFF0000u);
    return lo | hi;
#endif
}
// zero-extend bytes {0,1} / {2,3} of v into two u16 lanes (v_perm_b32, 0x0C=zero)
__device__ __forceinline__ unsigned int lo16x2(unsigned int v) {
#if __has_builtin(__builtin_amdgcn_perm)
    return __builtin_amdgcn_perm(0u, v, 0x0C010C00u);
#else
    return (v & 0xFFu) | ((v << 8) & 0x00FF0000u);
#endif
}
__device__ __forceinline__ unsigned int hi16x2(unsigned int v) {
#if __has_builtin(__builtin_amdgcn_perm)
    return __builtin_amdgcn_perm(0u, v, 0x0C030C02u);
#else
    return ((v >> 16) & 0xFFu) | ((v >> 8) & 0x00FF0000u);
#endif
}
// pack 4 row-maxes (u16 lanes of alo=rows01, ahi=rows23, values<=255) into u32
__device__ __forceinline__ unsigned int pack4(unsigned int alo, unsigned int ahi) {
#if __has_builtin(__builtin_amdgcn_perm)
    return __builtin_amdgcn_perm(ahi, alo, 0x06040200u); // alo.b0,alo.b2,ahi.b0,ahi.b2
#else
    return (alo & 0xFFu) | ((alo >> 8) & 0xFF00u)
         | ((ahi << 16) & 0xFF0000u) | ((ahi << 8) & 0xFF000000u);
#endif
}
// single v_rcp_f32. VERIFIED WIN round 2: 178.96 -> 159.24 us.
__device__ __forceinline__ float fast_rcp(float x) {
#if __has_builtin(__builtin_amdgcn_rcpf)
    return __builtin_amdgcn_rcpf(x);
#else
    return 1.0f / x;
#endif
}
// async global->LDS, 16B per lane; LDS dest = firstlane base + lane*16
__device__ __forceinline__ void gll16(const unsigned short* g, unsigned short* l) {
    __builtin_amdgcn_global_load_lds(
        (const __attribute__((address_space(1))) void*)g,
        (__attribute__((address_space(3))) void*)l, 16, 0, 0);
}

// ---------------------------------------------------------------------------
// prep1: blocks [0,1024): x f32 -> bf16 (2048 elems/block)
//        blocks [1024,1181): W[k][f] -> Wt[f][k] bf16, LDS-tiled
//        blocks [1181,1201): ELL init (all 16 slots = self), cur=1, ovf=0
// ---------------------------------------------------------------------------
__global__ __launch_bounds__(256) void prep1_kernel(
    const float* __restrict__ x, const float* __restrict__ W,
    unsigned short* __restrict__ xb, unsigned short* __restrict__ wt,
    unsigned short* __restrict__ ell, int* __restrict__ cur,
    int* __restrict__ ovf_cnt)
{
    __shared__ float lt[128][33];
    int bid = blockIdx.x, tid = threadIdx.x;
    if (bid < 1024) {
        size_t base = (size_t)bid * 2048 + (size_t)tid * 8;
        const f32x4* p = (const f32x4*)(x + base);
        f32x4 v0 = p[0], v1 = p[1];
        short8 o;
        o[0] = (short)f2bf(v0[0]); o[1] = (short)f2bf(v0[1]);
        o[2] = (short)f2bf(v0[2]); o[3] = (short)f2bf(v0[3]);
        o[4] = (short)f2bf(v1[0]); o[5] = (short)f2bf(v1[1]);
        o[6] = (short)f2bf(v1[2]); o[7] = (short)f2bf(v1[3]);
        *(short8*)(xb + base) = o;
    } else if (bid < 1181) {
        int f0 = (bid - 1024) * 32;
        int f_l = tid & 31, k0 = (tid >> 5) * 16;
        #pragma unroll
        for (int i = 0; i < 16; ++i) {
            int f = f0 + f_l;
            lt[k0 + i][f_l] = (f < FDIM) ? W[(size_t)(k0 + i) * FDIM + f] : 0.f;
        }
        __syncthreads();
        int f_l2 = tid >> 3, ks = (tid & 7) * 16;
        int f = f0 + f_l2;
        if (f < FDIM) {
            short8 o0, o1;
            #pragma unroll
            for (int j = 0; j < 8; ++j) o0[j] = (short)f2bf(lt[ks + j][f_l2]);
            #pragma unroll
            for (int j = 0; j < 8; ++j) o1[j] = (short)f2bf(lt[ks + 8 + j][f_l2]);
            *(short8*)(wt + (size_t)f * 128 + ks)     = o0;
            *(short8*)(wt + (size_t)f * 128 + ks + 8) = o1;
        }
    } else {
        int p = (bid - 1181) * 256 + tid;
        if (p < FDIM) {
            upk8 s;
            #pragma unroll
            for (int j = 0; j < 8; ++j) s[j] = (unsigned short)p;
            *(upk8*)(ell + (size_t)p * ELLW)     = s;
            *(upk8*)(ell + (size_t)p * ELLW + 8) = s;
            cur[p] = 1;
        }
        if (p == FDIM) *ovf_cnt = 0;
    }
}

// ---------------------------------------------------------------------------
// prep2: scatter children into ELL slots 1.. (order irrelevant: max).
// ---------------------------------------------------------------------------
__global__ __launch_bounds__(256) void prep2_kernel(
    const int* __restrict__ epar, const int* __restrict__ echild,
    int* __restrict__ cur, unsigned short* __restrict__ ell,
    int* __restrict__ ovf_cnt, int* __restrict__ ovf_pairs)
{
    int i = blockIdx.x * 256 + threadIdx.x;
    if (i < EDIM) {
        int p = epar[i], c = echild[i];
        if (p != c) {
            int pos = atomicAdd(&cur[p], 1);
            if (pos < ELLW) {
                ell[(size_t)p * ELLW + pos] = (unsigned short)c;
            } else {
                int j = atomicAdd(ovf_cnt, 1);
                if (j < MAXOVF) { ovf_pairs[2 * j] = p; ovf_pairs[2 * j + 1] = c; }
            }
        }
    }
}

// ---------------------------------------------------------------------------
// prep3: counting-sort parents by (capped) degree -> dgp[i] = perm<<8 | dg,
// and materialize permuted ELL rows. VERIFIED (r11).
// ---------------------------------------------------------------------------
__global__ __launch_bounds__(1024) void prep3_kernel(
    const int* __restrict__ cur, const unsigned short* __restrict__ ell,
    unsigned int* __restrict__ dgp, unsigned short* __restrict__ ellp)
{
    __shared__ int hist[32];
    __shared__ int base[32];
    int tid = threadIdx.x;
    if (tid < 32) hist[tid] = 0;
    __syncthreads();
    for (int p = tid; p < FDIM; p += 1024) {
        int d = cur[p]; if (d > 31) d = 31;
        atomicAdd(&hist[d], 1);
    }
    __syncthreads();
    if (tid == 0) {
        int acc = 0;
        for (int b = 0; b < 32; ++b) { base[b] = acc; acc += hist[b]; }
    }
    __syncthreads();
    for (int p = tid; p < FDIM; p += 1024) {
        int d = cur[p]; if (d > 31) d = 31;
        int pos = atomicAdd(&base[d], 1);
        int dcap = cur[p]; if (dcap > 255) dcap = 255;
        dgp[pos] = ((unsigned int)p << 8) | (unsigned int)dcap;
    }
    __syncthreads();   // dgp visible block-wide
    for (int i = tid; i < FDIM; i += 1024) {
        int pr = (int)(dgp[i] >> 8);
        upk8 lo = *(const upk8*)(ell + (size_t)pr * ELLW);
        upk8 hi = *(const upk8*)(ell + (size_t)pr * ELLW + 8);
        *(upk8*)(ellp + (size_t)i * ELLW)     = lo;
        *(upk8*)(ellp + (size_t)i * ELLW + 8) = hi;
    }
}

// ---------------------------------------------------------------------------
// gemm8u: EXACT r12/r13-verified version. u8 sigmoid-quant epilogue,
// half-slab layout [slab*2+(g&1)][FDIM][4].
// ---------------------------------------------------------------------------
__global__ __launch_bounds__(512, 4) void gemm8u_kernel(
    const unsigned short* __restrict__ xb,   // [BDIM][128] bf16
    const unsigned short* __restrict__ wt,   // [FDIM][128] bf16
    const float* __restrict__ bias,
    unsigned char* __restrict__ probs8)      // [BDIM/8*2][FDIM][4] u8
{
    __shared__ unsigned short lA[128 * 128];
    __shared__ unsigned short lB[128 * 128];

    int bid0 = blockIdx.x;
    int bid  = (bid0 & 7) * (128 * NT4 / 8) + (bid0 >> 3);   // XCD swizzle
    int bm = bid / NT4, bq = bid % NT4;
    int tid = threadIdx.x;
    int lane = tid & 63, w = tid >> 6;       // 8 waves
    int wm = w >> 2, wn = w & 3;
    int g = lane >> 4, lr = lane & 15;
    int lrow = lane >> 4;                    // row within 4-row chunk
    int lcol = (lane & 15) << 4;             // byte col

    auto stageA = [&]() {
        #pragma unroll
        for (int it = 0; it < 4; ++it) {
            int ci = w * 4 + it;             // chunk 0..31
            int row = ci * 4 + lrow;
            int sw = lcol ^ ((row & 7) << 4);
            gll16(xb + ((size_t)(bm * 128 + row) << 7) + (sw >> 1),
                  lA + ci * 512);
        }
    };
    auto stageB = [&](int bn) {
        #pragma unroll
        for (int it = 0; it < 4; ++it) {
            int ci = w * 4 + it;
            int row = ci * 4 + lrow;
            int sw = lcol ^ ((row & 7) << 4);
            gll16(wt + ((size_t)(bn * 128 + row) << 7) + (sw >> 1),
                  lB + ci * 512);
        }
    };
    auto compute = [&](f32x4 (&acc)[4][2]) {
        #pragma unroll
        for (int ks = 0; ks < 4; ++ks) {
            int cbk = ks * 64 + g * 16;
            short8 af[4], bf[2];
            #pragma unroll
            for (int mi = 0; mi < 4; ++mi) {
                int row = wm * 64 + mi * 16 + lr;
                af[mi] = *(const short8*)((const char*)lA + row * 256 + (cbk ^ ((row & 7) << 4)));
            }
            #pragma unroll
            for (int nj = 0; nj < 2; ++nj) {
                int row = wn * 32 + nj * 16 + lr;
                bf[nj] = *(const short8*)((const char*)lB + row * 256 + (cbk ^ ((row & 7) << 4)));
            }
            #pragma unroll
            for (int mi = 0; mi < 4; ++mi)
                #pragma unroll
                for (int nj = 0; nj < 2; ++nj)
                    acc[mi][nj] = __builtin_amdgcn_mfma_f32_16x16x32_bf16(
                        af[mi], bf[nj], acc[mi][nj], 0, 0, 0);
        }
    };
    auto epilogue = [&](int bn, f32x4 (&acc)[4][2]) {
        #pragma unroll
        for (int nj = 0; nj < 2; ++nj) {
            int f = bn * 128 + wn * 32 + nj * 16 + lr;
            bool ok = (f < FDIM);
            float bb = ok ? bias[f] : 0.f;
            #pragma unroll
            for (int mi = 0; mi < 4; ++mi) {
                unsigned int pk = 0;
                #pragma unroll
                for (int j = 0; j < 4; ++j) {
                    float z = acc[mi][nj][j] + bb;
                    float pr = fast_rcp(1.0f + __expf(-z));   // v_rcp_f32
                    unsigned int q = (unsigned int)(pr * 255.f + 0.5f);
                    pk |= q << (8 * j);
                }
                if (ok) {
                    int slab = bm * 16 + wm * 8 + mi * 2 + (g >> 1);
                    int grp  = slab * 2 + (g & 1);   // half-slab group
                    *(unsigned int*)(probs8 + ((size_t)grp * FDIM + f) * 4) = pk;
                }
            }
        }
    };

    stageA();
    stageB(bq * 4);
    __syncthreads();                     // drains vmcnt -> tiles resident

    f32x4 zero = {0.f, 0.f, 0.f, 0.f};
    for (int t = 0; t < 4; ++t) {
        f32x4 acc[4][2];
        #pragma unroll
        for (int mi = 0; mi < 4; ++mi) { acc[mi][0] = zero; acc[mi][1] = zero; }
        compute(acc);
        if (t < 3) {
            __syncthreads();             // all waves done reading lB(t)
            stageB(bq * 4 + t + 1);      // async B(t+1), hides under epilogue
            epilogue(bq * 4 + t, acc);
            __syncthreads();             // drains vmcnt -> lB(t+1) ready
        } else {
            epilogue(bq * 4 + t, acc);
        }
    }
}

// ---------------------------------------------------------------------------
// segmax20: r13-verified gather math at 512 threads / 4 blocks per CU.
// (a) exchange packs the 4 row-maxes (<=255) into ONE u32 via v_perm_b32
//     -> xpk is 20KB; LDS/block = 20000+20000 = 40000B -> 4 blocks/CU
//     (4 x 8 waves = 32 = wave cap) vs 2 x 1024-thread blocks before.
// (b) finer phase granularity: at any instant some resident block is in
//     its store phase (feeding HBM) while others gather (feeding LDS) --
//     attacks the ~28us phase-overlap deficit (seg ~90 vs ~62 HBM floor).
// Canonical unpack: v_cvt_f32_ubyteN per value. Integers identical ->
// absmax exactly 0.005859375.
// ---------------------------------------------------------------------------
__global__ __launch_bounds__(512, 8) void segmax20_kernel(
    const unsigned char* __restrict__ probs8,    // [4096][FDIM][4] u8
    const unsigned int* __restrict__ dgp,        // [FDIM] perm<<8|dg (sorted)
    const unsigned short* __restrict__ ellp,     // [FDIM][16] permuted ELL
    const int* __restrict__ ovf_cnt, const int* __restrict__ ovf_pairs,
    float* __restrict__ out)
{
    __shared__ unsigned int l32[FDIM];           // 20000 B raw u8 rows
    __shared__ unsigned int xpk[FDIM];           // 20000 B packed 4-row maxes
    int grp = blockIdx.x;                        // half-slab group
    int b0 = (grp >> 1) * 8 + (grp & 1) * 4;     // first of 4 batch rows
    int tid = threadIdx.x;
    const unsigned short* src =
        (const unsigned short*)(probs8 + (size_t)grp * FDIM * 4);

    for (int c = tid; c < FDIM / 4; c += 512) {  // 1250 x 16B chunks
        gll16(src + (size_t)c * 8, (unsigned short*)l32 + (size_t)c * 8);
    }
    __syncthreads();                             // table resident

    int novf = *ovf_cnt; if (novf > MAXOVF) novf = MAXOVF;

    // ---- gather phase: sorted order, 2 parents/thread/iter ----
    for (int w0 = tid * 2; w0 < FDIM; w0 += 1024) {
        int w1 = w0 + 1;
        u32x2 dv = *(const u32x2*)(dgp + w0);
        int pa = (int)(dv[0] >> 8), da = (int)(dv[0] & 255u);
        int pb = (int)(dv[1] >> 8), db = (int)(dv[1] & 255u);
        upk8 ea = *(const upk8*)(ellp + (size_t)w0 * ELLW);   // slots 0-7
        upk8 eb = *(const upk8*)(ellp + (size_t)w1 * ELLW);
        unsigned int va = l32[ea[0]], vb = l32[eb[0]];
        unsigned int alo = lo16x2(va), ahi = hi16x2(va);
        unsigned int blo = lo16x2(vb), bhi = hi16x2(vb);
        #pragma unroll
        for (int s = 1; s < 4; ++s) {
            unsigned int u = l32[ea[s]], v = l32[eb[s]];
            alo = pkmax2(alo, lo16x2(u)); ahi = pkmax2(ahi, hi16x2(u));
            blo = pkmax2(blo, lo16x2(v)); bhi = pkmax2(bhi, hi16x2(v));
        }
        if (da > 4) {
            #pragma unroll
            for (int s = 4; s < 8; ++s) {
                unsigned int u = l32[ea[s]];
                alo = pkmax2(alo, lo16x2(u)); ahi = pkmax2(ahi, hi16x2(u));
            }
        }
        if (db > 4) {
            #pragma unroll
            for (int s = 4; s < 8; ++s) {
                unsigned int v = l32[eb[s]];
                blo = pkmax2(blo, lo16x2(v)); bhi = pkmax2(bhi, hi16x2(v));
            }
        }
        if (da > 8) {
            upk8 e = *(const upk8*)(ellp + (size_t)w0 * ELLW + 8);
            #pragma unroll
            for (int k = 0; k < 8; ++k) {
                unsigned int u = l32[e[k]];
                alo = pkmax2(alo, lo16x2(u)); ahi = pkmax2(ahi, hi16x2(u));
            }
        }
        if (db > 8) {
            upk8 e = *(const upk8*)(ellp + (size_t)w1 * ELLW + 8);
            #pragma unroll
            for (int k = 0; k < 8; ++k) {
                unsigned int v = l32[e[k]];
                blo = pkmax2(blo, lo16x2(v)); bhi = pkmax2(bhi, hi16x2(v));
            }
        }
        if (da > ELLW) {
            for (int i = 0; i < novf; ++i)
                if (ovf_pairs[2 * i] == pa) {
                    unsigned int u = l32[ovf_pairs[2 * i + 1]];
                    alo = pkmax2(alo, lo16x2(u)); ahi = pkmax2(ahi, hi16x2(u));
                }
        }
        if (db > ELLW) {
            for (int i = 0; i < novf; ++i)
                if (ovf_pairs[2 * i] == pb) {
                    unsigned int v = l32[ovf_pairs[2 * i + 1]];
                    blo = pkmax2(blo, lo16x2(v)); bhi = pkmax2(bhi, hi16x2(v));
                }
        }
        xpk[pa] = pack4(alo, ahi);
        xpk[pb] = pack4(blo, bhi);
    }
    __syncthreads();                             // exchange complete

    // ---- canonical phase: 4 adjacent parents/thread, f32x4 stores ----
    for (int p0 = tid * 4; p0 < FDIM; p0 += 2048) {   // 5000%4==0
        u32x4 pk4 = *(const u32x4*)(xpk + p0);
        size_t o = (size_t)b0 * FDIM + p0;
        #pragma unroll
        for (int r = 0; r < 4; ++r) {
            f32x4 v4;
            #pragma unroll
            for (int j = 0; j < 4; ++j) {
                unsigned int q = (pk4[j] >> (8 * r)) & 0xFFu;  // v_cvt_f32_ubyteN
                v4[j] = (float)q * (1.f / 255.f);
            }
            __builtin_nontemporal_store(v4, (f32x4*)(out + o + (size_t)r * FDIM));
        }
    }
}

// ---------------------------------------------------------------------------
extern "C" void kernel_launch(void* const* d_in, const int* in_sizes, int n_in,
                              void* d_out, int out_size, void* d_ws, size_t ws_size,
                              hipStream_t stream)
{
    const float* x     = (const float*)d_in[0];
    const float* W     = (const float*)d_in[1];
    const float* bias  = (const float*)d_in[2];
    const int*   epar  = (const int*)d_in[3];
    const int*   echild= (const int*)d_in[4];
    float* out = (float*)d_out;

    char* ws = (char*)d_ws;
    size_t off = 0;
    auto alloc = [&](size_t bytes) { size_t o = off; off = (off + bytes + 255) & ~(size_t)255; return o; };
    size_t o_probs  = alloc((size_t)BDIM * FDIM);        // u8 (half-slab layout)
    size_t o_xb     = alloc((size_t)BDIM * CDIM * 2);
    size_t o_wt     = alloc((size_t)FDIM * CDIM * 2);
    size_t o_ell    = alloc((size_t)FDIM * ELLW * 2);
    size_t o_cur    = alloc((size_t)FDIM * 4);
    size_t o_ovfc   = alloc(4);
    size_t o_ovfp   = alloc((size_t)MAXOVF * 8);
    size_t o_dgp    = alloc((size_t)FDIM * 4);
    size_t o_ellp   = alloc((size_t)FDIM * ELLW * 2);
    (void)ws_size; (void)in_sizes; (void)n_in; (void)out_size;

    unsigned char*  probs8 = (unsigned char*)(ws + o_probs);
    unsigned short* xb     = (unsigned short*)(ws + o_xb);
    unsigned short* wt     = (unsigned short*)(ws + o_wt);
    unsigned short* ell    = (unsigned short*)(ws + o_ell);
    int* cur      = (int*)(ws + o_cur);
    int* ovf_cnt  = (int*)(ws + o_ovfc);
    int* ovf_pairs= (int*)(ws + o_ovfp);
    unsigned int*   dgp  = (unsigned int*)(ws + o_dgp);
    unsigned short* ellp = (unsigned short*)(ws + o_ellp);

    prep1_kernel<<<1201, 256, 0, stream>>>(x, W, xb, wt, ell, cur, ovf_cnt);
    prep2_kernel<<<79, 256, 0, stream>>>(epar, echild, cur, ell, ovf_cnt, ovf_pairs);
    prep3_kernel<<<1, 1024, 0, stream>>>(cur, ell, dgp, ellp);
    gemm8u_kernel<<<128 * NT4, 512, 0, stream>>>(xb, wt, bias, probs8);
    segmax20_kernel<<<BDIM / 8 * 2, 512, 0, stream>>>(probs8, dgp, ellp,
                                                      ovf_cnt, ovf_pairs, out);
}

// Round 15
// 143.220 us; speedup vs baseline: 1.0332x; 1.0332x over previous
//
#include <hip/hip_runtime.h>
#include <hip/hip_bf16.h>

#define BDIM 16384
#define CDIM 128
#define FDIM 5000
#define EDIM 20000
#define ELLW 16
#define MAXOVF 20000
#define NT4  10       // n-tile QUADS: 40 n-tiles / 4

typedef __attribute__((ext_vector_type(8))) short short8;
typedef __attribute__((ext_vector_type(4))) float f32x4;
typedef __attribute__((ext_vector_type(2))) float f32x2;
typedef __attribute__((ext_vector_type(2))) int i32x2;
typedef __attribute__((ext_vector_type(8))) unsigned short upk8;
typedef __attribute__((ext_vector_type(4))) unsigned short upk4;
typedef __attribute__((ext_vector_type(2))) unsigned short upk2;
typedef __attribute__((ext_vector_type(2))) unsigned int u32x2;
typedef __attribute__((ext_vector_type(4))) unsigned int u32x4;

__device__ __forceinline__ unsigned short f2bf(float f) {
    unsigned int u = __builtin_bit_cast(unsigned int, f);
    u = (u + 0x7fffu + ((u >> 16) & 1u)) >> 16;   // RNE
    return (unsigned short)u;
}
// packed max of two u16 pairs (v_pk_max_u16)
__device__ __forceinline__ unsigned int pkmax2(unsigned int a, unsigned int b) {
#if __has_builtin(__builtin_elementwise_max)
    upk2 r = __builtin_elementwise_max(__builtin_bit_cast(upk2, a),
                                       __builtin_bit_cast(upk2, b));
    return __builtin_bit_cast(unsigned int, r);
#else
    unsigned int lo = ((a & 0xFFFFu) > (b & 0xFFFFu)) ? (a & 0xFFFFu) : (b & 0xFFFFu);
    unsigned int hi = ((a >> 16) > (b >> 16)) ? (a & 0xFFFF0000u) : (b & 0xFFFF0000u);
    return lo | hi;
#endif
}
// zero-extend bytes {0,1} / {2,3} of v into two u16 lanes (v_perm_b32, 0x0C=zero)
__device__ __forceinline__ unsigned int lo16x2(unsigned int v) {
#if __has_builtin(__builtin_amdgcn_perm)
    return __builtin_amdgcn_perm(0u, v, 0x0C010C00u);
#else
    return (v & 0xFFu) | ((v << 8) & 0x00FF0000u);
#endif
}
__device__ __forceinline__ unsigned int hi16x2(unsigned int v) {
#if __has_builtin(__builtin_amdgcn_perm)
    return __builtin_amdgcn_perm(0u, v, 0x0C030C02u);
#else
    return ((v >> 16) & 0xFFu) | ((v >> 8) & 0x00FF0000u);
#endif
}
// single v_rcp_f32. VERIFIED WIN round 2: 178.96 -> 159.24 us.
__device__ __forceinline__ float fast_rcp(float x) {
#if __has_builtin(__builtin_amdgcn_rcpf)
    return __builtin_amdgcn_rcpf(x);
#else
    return 1.0f / x;
#endif
}
// async global->LDS, 16B per lane; LDS dest = firstlane base + lane*16
__device__ __forceinline__ void gll16(const unsigned short* g, unsigned short* l) {
    __builtin_amdgcn_global_load_lds(
        (const __attribute__((address_space(1))) void*)g,
        (__attribute__((address_space(3))) void*)l, 16, 0, 0);
}

// ---------------------------------------------------------------------------
// prep1: blocks [0,1024): x f32 -> bf16 (2048 elems/block)
//        blocks [1024,1181): W[k][f] -> Wt[f][k] bf16, LDS-tiled
//        blocks [1181,1201): ELL init (all 16 slots = self), cur=1, ovf=0
// ---------------------------------------------------------------------------
__global__ __launch_bounds__(256) void prep1_kernel(
    const float* __restrict__ x, const float* __restrict__ W,
    unsigned short* __restrict__ xb, unsigned short* __restrict__ wt,
    unsigned short* __restrict__ ell, int* __restrict__ cur,
    int* __restrict__ ovf_cnt)
{
    __shared__ float lt[128][33];
    int bid = blockIdx.x, tid = threadIdx.x;
    if (bid < 1024) {
        size_t base = (size_t)bid * 2048 + (size_t)tid * 8;
        const f32x4* p = (const f32x4*)(x + base);
        f32x4 v0 = p[0], v1 = p[1];
        short8 o;
        o[0] = (short)f2bf(v0[0]); o[1] = (short)f2bf(v0[1]);
        o[2] = (short)f2bf(v0[2]); o[3] = (short)f2bf(v0[3]);
        o[4] = (short)f2bf(v1[0]); o[5] = (short)f2bf(v1[1]);
        o[6] = (short)f2bf(v1[2]); o[7] = (short)f2bf(v1[3]);
        *(short8*)(xb + base) = o;
    } else if (bid < 1181) {
        int f0 = (bid - 1024) * 32;
        int f_l = tid & 31, k0 = (tid >> 5) * 16;
        #pragma unroll
        for (int i = 0; i < 16; ++i) {
            int f = f0 + f_l;
            lt[k0 + i][f_l] = (f < FDIM) ? W[(size_t)(k0 + i) * FDIM + f] : 0.f;
        }
        __syncthreads();
        int f_l2 = tid >> 3, ks = (tid & 7) * 16;
        int f = f0 + f_l2;
        if (f < FDIM) {
            short8 o0, o1;
            #pragma unroll
            for (int j = 0; j < 8; ++j) o0[j] = (short)f2bf(lt[ks + j][f_l2]);
            #pragma unroll
            for (int j = 0; j < 8; ++j) o1[j] = (short)f2bf(lt[ks + 8 + j][f_l2]);
            *(short8*)(wt + (size_t)f * 128 + ks)     = o0;
            *(short8*)(wt + (size_t)f * 128 + ks + 8) = o1;
        }
    } else {
        int p = (bid - 1181) * 256 + tid;
        if (p < FDIM) {
            upk8 s;
            #pragma unroll
            for (int j = 0; j < 8; ++j) s[j] = (unsigned short)p;
            *(upk8*)(ell + (size_t)p * ELLW)     = s;
            *(upk8*)(ell + (size_t)p * ELLW + 8) = s;
            cur[p] = 1;
        }
        if (p == FDIM) *ovf_cnt = 0;
    }
}

// ---------------------------------------------------------------------------
// prep2: scatter children into ELL slots 1.. (order irrelevant: max).
// ---------------------------------------------------------------------------
__global__ __launch_bounds__(256) void prep2_kernel(
    const int* __restrict__ epar, const int* __restrict__ echild,
    int* __restrict__ cur, unsigned short* __restrict__ ell,
    int* __restrict__ ovf_cnt, int* __restrict__ ovf_pairs)
{
    int i = blockIdx.x * 256 + threadIdx.x;
    if (i < EDIM) {
        int p = epar[i], c = echild[i];
        if (p != c) {
            int pos = atomicAdd(&cur[p], 1);
            if (pos < ELLW) {
                ell[(size_t)p * ELLW + pos] = (unsigned short)c;
            } else {
                int j = atomicAdd(ovf_cnt, 1);
                if (j < MAXOVF) { ovf_pairs[2 * j] = p; ovf_pairs[2 * j + 1] = c; }
            }
        }
    }
}

// ---------------------------------------------------------------------------
// prep3: counting-sort parents by (capped) degree -> dgp[i] = perm<<8 | dg,
// and materialize permuted ELL rows. VERIFIED (r11).
// ---------------------------------------------------------------------------
__global__ __launch_bounds__(1024) void prep3_kernel(
    const int* __restrict__ cur, const unsigned short* __restrict__ ell,
    unsigned int* __restrict__ dgp, unsigned short* __restrict__ ellp)
{
    __shared__ int hist[32];
    __shared__ int base[32];
    int tid = threadIdx.x;
    if (tid < 32) hist[tid] = 0;
    __syncthreads();
    for (int p = tid; p < FDIM; p += 1024) {
        int d = cur[p]; if (d > 31) d = 31;
        atomicAdd(&hist[d], 1);
    }
    __syncthreads();
    if (tid == 0) {
        int acc = 0;
        for (int b = 0; b < 32; ++b) { base[b] = acc; acc += hist[b]; }
    }
    __syncthreads();
    for (int p = tid; p < FDIM; p += 1024) {
        int d = cur[p]; if (d > 31) d = 31;
        int pos = atomicAdd(&base[d], 1);
        int dcap = cur[p]; if (dcap > 255) dcap = 255;
        dgp[pos] = ((unsigned int)p << 8) | (unsigned int)dcap;
    }
    __syncthreads();   // dgp visible block-wide
    for (int i = tid; i < FDIM; i += 1024) {
        int pr = (int)(dgp[i] >> 8);
        upk8 lo = *(const upk8*)(ell + (size_t)pr * ELLW);
        upk8 hi = *(const upk8*)(ell + (size_t)pr * ELLW + 8);
        *(upk8*)(ellp + (size_t)i * ELLW)     = lo;
        *(upk8*)(ellp + (size_t)i * ELLW + 8) = hi;
    }
}

// ---------------------------------------------------------------------------
// gemm8u: EXACT r12/r13-verified version. u8 sigmoid-quant epilogue,
// half-slab layout [slab*2+(g&1)][FDIM][4].
// ---------------------------------------------------------------------------
__global__ __launch_bounds__(512, 4) void gemm8u_kernel(
    const unsigned short* __restrict__ xb,   // [BDIM][128] bf16
    const unsigned short* __restrict__ wt,   // [FDIM][128] bf16
    const float* __restrict__ bias,
    unsigned char* __restrict__ probs8)      // [BDIM/8*2][FDIM][4] u8
{
    __shared__ unsigned short lA[128 * 128];
    __shared__ unsigned short lB[128 * 128];

    int bid0 = blockIdx.x;
    int bid  = (bid0 & 7) * (128 * NT4 / 8) + (bid0 >> 3);   // XCD swizzle
    int bm = bid / NT4, bq = bid % NT4;
    int tid = threadIdx.x;
    int lane = tid & 63, w = tid >> 6;       // 8 waves
    int wm = w >> 2, wn = w & 3;
    int g = lane >> 4, lr = lane & 15;
    int lrow = lane >> 4;                    // row within 4-row chunk
    int lcol = (lane & 15) << 4;             // byte col

    auto stageA = [&]() {
        #pragma unroll
        for (int it = 0; it < 4; ++it) {
            int ci = w * 4 + it;             // chunk 0..31
            int row = ci * 4 + lrow;
            int sw = lcol ^ ((row & 7) << 4);
            gll16(xb + ((size_t)(bm * 128 + row) << 7) + (sw >> 1),
                  lA + ci * 512);
        }
    };
    auto stageB = [&](int bn) {
        #pragma unroll
        for (int it = 0; it < 4; ++it) {
            int ci = w * 4 + it;
            int row = ci * 4 + lrow;
            int sw = lcol ^ ((row & 7) << 4);
            gll16(wt + ((size_t)(bn * 128 + row) << 7) + (sw >> 1),
                  lB + ci * 512);
        }
    };
    auto compute = [&](f32x4 (&acc)[4][2]) {
        #pragma unroll
        for (int ks = 0; ks < 4; ++ks) {
            int cbk = ks * 64 + g * 16;
            short8 af[4], bf[2];
            #pragma unroll
            for (int mi = 0; mi < 4; ++mi) {
                int row = wm * 64 + mi * 16 + lr;
                af[mi] = *(const short8*)((const char*)lA + row * 256 + (cbk ^ ((row & 7) << 4)));
            }
            #pragma unroll
            for (int nj = 0; nj < 2; ++nj) {
                int row = wn * 32 + nj * 16 + lr;
                bf[nj] = *(const short8*)((const char*)lB + row * 256 + (cbk ^ ((row & 7) << 4)));
            }
            #pragma unroll
            for (int mi = 0; mi < 4; ++mi)
                #pragma unroll
                for (int nj = 0; nj < 2; ++nj)
                    acc[mi][nj] = __builtin_amdgcn_mfma_f32_16x16x32_bf16(
                        af[mi], bf[nj], acc[mi][nj], 0, 0, 0);
        }
    };
    auto epilogue = [&](int bn, f32x4 (&acc)[4][2]) {
        #pragma unroll
        for (int nj = 0; nj < 2; ++nj) {
            int f = bn * 128 + wn * 32 + nj * 16 + lr;
            bool ok = (f < FDIM);
            float bb = ok ? bias[f] : 0.f;
            #pragma unroll
            for (int mi = 0; mi < 4; ++mi) {
                unsigned int pk = 0;
                #pragma unroll
                for (int j = 0; j < 4; ++j) {
                    float z = acc[mi][nj][j] + bb;
                    float pr = fast_rcp(1.0f + __expf(-z));   // v_rcp_f32
                    unsigned int q = (unsigned int)(pr * 255.f + 0.5f);
                    pk |= q << (8 * j);
                }
                if (ok) {
                    int slab = bm * 16 + wm * 8 + mi * 2 + (g >> 1);
                    int grp  = slab * 2 + (g & 1);   // half-slab group
                    *(unsigned int*)(probs8 + ((size_t)grp * FDIM + f) * 4) = pk;
                }
            }
        }
    };

    stageA();
    stageB(bq * 4);
    __syncthreads();                     // drains vmcnt -> tiles resident

    f32x4 zero = {0.f, 0.f, 0.f, 0.f};
    for (int t = 0; t < 4; ++t) {
        f32x4 acc[4][2];
        #pragma unroll
        for (int mi = 0; mi < 4; ++mi) { acc[mi][0] = zero; acc[mi][1] = zero; }
        compute(acc);
        if (t < 3) {
            __syncthreads();             // all waves done reading lB(t)
            stageB(bq * 4 + t + 1);      // async B(t+1), hides under epilogue
            epilogue(bq * 4 + t, acc);
            __syncthreads();             // drains vmcnt -> lB(t+1) ready
        } else {
            epilogue(bq * 4 + t, acc);
        }
    }
}

// ---------------------------------------------------------------------------
// segmax19c: EXACT r13-verified seg (143.29 us: u8 table, b32 conflict-free
// gathers, u16-pair max, sorted order, xlo/xhi exchange, 1024 threads,
// 60000B LDS -> 2 blocks/CU) with ONE change: the 328MB output stores are
// REGULAR (cached) f32x4 stores, not nontemporal. nt bypasses L2 -> the
// store phase stalls on direct-HBM round trips; cached stores let L2/L3
// absorb the burst and drain under the next block's stage/gather phases
// (evidence: harness poison-fills hit 6.8 TB/s with regular stores at 10%
// occupancy; seg's effective write BW is only ~3.7 TB/s). Never-ablated
// since r0. Bit-identical output.
// ---------------------------------------------------------------------------
__global__ __launch_bounds__(1024) void segmax19c_kernel(
    const unsigned char* __restrict__ probs8,    // [4096][FDIM][4] u8
    const unsigned int* __restrict__ dgp,        // [FDIM] perm<<8|dg (sorted)
    const unsigned short* __restrict__ ellp,     // [FDIM][16] permuted ELL
    const int* __restrict__ ovf_cnt, const int* __restrict__ ovf_pairs,
    float* __restrict__ out)
{
    __shared__ unsigned int l32[FDIM];           // 20000 B raw u8 rows
    __shared__ unsigned int xlo[FDIM];           // 20000 B acc lo (rows 0,1)
    __shared__ unsigned int xhi[FDIM];           // 20000 B acc hi (rows 2,3)
    int grp = blockIdx.x;                        // half-slab group
    int b0 = (grp >> 1) * 8 + (grp & 1) * 4;     // first of 4 batch rows
    int tid = threadIdx.x;
    const unsigned short* src =
        (const unsigned short*)(probs8 + (size_t)grp * FDIM * 4);

    for (int c = tid; c < FDIM / 4; c += 1024) { // 1250 x 16B chunks
        gll16(src + (size_t)c * 8, (unsigned short*)l32 + (size_t)c * 8);
    }
    __syncthreads();                             // table resident

    int novf = *ovf_cnt; if (novf > MAXOVF) novf = MAXOVF;

    // ---- gather phase: sorted order, 2 parents/thread/iter ----
    for (int w0 = tid * 2; w0 < FDIM; w0 += 2048) {
        int w1 = w0 + 1;
        u32x2 dv = *(const u32x2*)(dgp + w0);
        int pa = (int)(dv[0] >> 8), da = (int)(dv[0] & 255u);
        int pb = (int)(dv[1] >> 8), db = (int)(dv[1] & 255u);
        upk8 ea = *(const upk8*)(ellp + (size_t)w0 * ELLW);   // slots 0-7
        upk8 eb = *(const upk8*)(ellp + (size_t)w1 * ELLW);
        unsigned int va = l32[ea[0]], vb = l32[eb[0]];
        unsigned int alo = lo16x2(va), ahi = hi16x2(va);
        unsigned int blo = lo16x2(vb), bhi = hi16x2(vb);
        #pragma unroll
        for (int s = 1; s < 4; ++s) {
            unsigned int u = l32[ea[s]], v = l32[eb[s]];
            alo = pkmax2(alo, lo16x2(u)); ahi = pkmax2(ahi, hi16x2(u));
            blo = pkmax2(blo, lo16x2(v)); bhi = pkmax2(bhi, hi16x2(v));
        }
        if (da > 4) {
            #pragma unroll
            for (int s = 4; s < 8; ++s) {
                unsigned int u = l32[ea[s]];
                alo = pkmax2(alo, lo16x2(u)); ahi = pkmax2(ahi, hi16x2(u));
            }
        }
        if (db > 4) {
            #pragma unroll
            for (int s = 4; s < 8; ++s) {
                unsigned int v = l32[eb[s]];
                blo = pkmax2(blo, lo16x2(v)); bhi = pkmax2(bhi, hi16x2(v));
            }
        }
        if (da > 8) {
            upk8 e = *(const upk8*)(ellp + (size_t)w0 * ELLW + 8);
            #pragma unroll
            for (int k = 0; k < 8; ++k) {
                unsigned int u = l32[e[k]];
                alo = pkmax2(alo, lo16x2(u)); ahi = pkmax2(ahi, hi16x2(u));
            }
        }
        if (db > 8) {
            upk8 e = *(const upk8*)(ellp + (size_t)w1 * ELLW + 8);
            #pragma unroll
            for (int k = 0; k < 8; ++k) {
                unsigned int v = l32[e[k]];
                blo = pkmax2(blo, lo16x2(v)); bhi = pkmax2(bhi, hi16x2(v));
            }
        }
        if (da > ELLW) {
            for (int i = 0; i < novf; ++i)
                if (ovf_pairs[2 * i] == pa) {
                    unsigned int u = l32[ovf_pairs[2 * i + 1]];
                    alo = pkmax2(alo, lo16x2(u)); ahi = pkmax2(ahi, hi16x2(u));
                }
        }
        if (db > ELLW) {
            for (int i = 0; i < novf; ++i)
                if (ovf_pairs[2 * i] == pb) {
                    unsigned int v = l32[ovf_pairs[2 * i + 1]];
                    blo = pkmax2(blo, lo16x2(v)); bhi = pkmax2(bhi, hi16x2(v));
                }
        }
        xlo[pa] = alo; xhi[pa] = ahi;
        xlo[pb] = blo; xhi[pb] = bhi;
    }
    __syncthreads();                             // exchange complete

    // ---- canonical phase: 4 adjacent parents/thread, f32x4 CACHED stores ----
    for (int p0 = tid * 4; p0 < FDIM; p0 += 4096) {   // 5000%4==0
        u32x4 lo4 = *(const u32x4*)(xlo + p0);
        u32x4 hi4 = *(const u32x4*)(xhi + p0);
        size_t o = (size_t)b0 * FDIM + p0;
        #pragma unroll
        for (int r = 0; r < 4; ++r) {
            f32x4 v4;
            #pragma unroll
            for (int j = 0; j < 4; ++j) {
                unsigned int w = (r < 2) ? lo4[j] : hi4[j];
                unsigned int q = (w >> (16 * (r & 1))) & 0xFFFFu;
                v4[j] = (float)q * (1.f / 255.f);
            }
            *(f32x4*)(out + o + (size_t)r * FDIM) = v4;   // regular store (L2)
        }
    }
}

// ---------------------------------------------------------------------------
extern "C" void kernel_launch(void* const* d_in, const int* in_sizes, int n_in,
                              void* d_out, int out_size, void* d_ws, size_t ws_size,
                              hipStream_t stream)
{
    const float* x     = (const float*)d_in[0];
    const float* W     = (const float*)d_in[1];
    const float* bias  = (const float*)d_in[2];
    const int*   epar  = (const int*)d_in[3];
    const int*   echild= (const int*)d_in[4];
    float* out = (float*)d_out;

    char* ws = (char*)d_ws;
    size_t off = 0;
    auto alloc = [&](size_t bytes) { size_t o = off; off = (off + bytes + 255) & ~(size_t)255; return o; };
    size_t o_probs  = alloc((size_t)BDIM * FDIM);        // u8 (half-slab layout)
    size_t o_xb     = alloc((size_t)BDIM * CDIM * 2);
    size_t o_wt     = alloc((size_t)FDIM * CDIM * 2);
    size_t o_ell    = alloc((size_t)FDIM * ELLW * 2);
    size_t o_cur    = alloc((size_t)FDIM * 4);
    size_t o_ovfc   = alloc(4);
    size_t o_ovfp   = alloc((size_t)MAXOVF * 8);
    size_t o_dgp    = alloc((size_t)FDIM * 4);
    size_t o_ellp   = alloc((size_t)FDIM * ELLW * 2);
    (void)ws_size; (void)in_sizes; (void)n_in; (void)out_size;

    unsigned char*  probs8 = (unsigned char*)(ws + o_probs);
    unsigned short* xb     = (unsigned short*)(ws + o_xb);
    unsigned short* wt     = (unsigned short*)(ws + o_wt);
    unsigned short* ell    = (unsigned short*)(ws + o_ell);
    int* cur      = (int*)(ws + o_cur);
    int* ovf_cnt  = (int*)(ws + o_ovfc);
    int* ovf_pairs= (int*)(ws + o_ovfp);
    unsigned int*   dgp  = (unsigned int*)(ws + o_dgp);
    unsigned short* ellp = (unsigned short*)(ws + o_ellp);

    prep1_kernel<<<1201, 256, 0, stream>>>(x, W, xb, wt, ell, cur, ovf_cnt);
    prep2_kernel<<<79, 256, 0, stream>>>(epar, echild, cur, ell, ovf_cnt, ovf_pairs);
    prep3_kernel<<<1, 1024, 0, stream>>>(cur, ell, dgp, ellp);
    gemm8u_kernel<<<128 * NT4, 512, 0, stream>>>(xb, wt, bias, probs8);
    segmax19c_kernel<<<BDIM / 8 * 2, 1024, 0, stream>>>(probs8, dgp, ellp,
                                                        ovf_cnt, ovf_pairs, out);
}